// Round 10
// baseline (370.007 us; speedup 1.0000x reference)
//
#include <hip/hip_runtime.h>
#include <math.h>

typedef _Float16 f16;
typedef _Float16 f16x8 __attribute__((ext_vector_type(8)));
typedef float f32x4 __attribute__((ext_vector_type(4)));

#define DIM 1024
enum { EPI_K = 0, EPI_V = 1 };

__device__ __forceinline__ float phi_f(float x) {
  return x > 0.f ? x + 1.f : __expf(x);  // elu(x)+1
}

// global -> LDS direct DMA, 16 B per lane, wave-uniform LDS base.
typedef __attribute__((address_space(1))) const void gconst_t;
typedef __attribute__((address_space(3))) void lds_t;
__device__ __forceinline__ void g2l16(const void* g, void* l) {
  __builtin_amdgcn_global_load_lds((gconst_t*)(uintptr_t)g, (lds_t*)(uintptr_t)l, 16, 0, 0);
}

// XCD-bijective swizzle for grid (8, MT).
template <int MT>
__device__ __forceinline__ void swz(int& nb, int& mb) {
  int flat = blockIdx.y * 8 + blockIdx.x;
  int wk = (flat & 7) * MT + (flat >> 3);
  nb = wk & 7;
  mb = wk >> 3;
}

// ---------------- fp32 -> fp16 convert (weights) ----------------
__global__ __launch_bounds__(256) void cvt8(const float* __restrict__ src,
                                            f16* __restrict__ dst) {
  size_t i = ((size_t)blockIdx.x * 256 + threadIdx.x) * 8;
  float4 a = *(const float4*)(src + i);
  float4 b = *(const float4*)(src + i + 4);
  union { f16 h[8]; uint4 u; } p;
  p.h[0] = (f16)a.x; p.h[1] = (f16)a.y; p.h[2] = (f16)a.z; p.h[3] = (f16)a.w;
  p.h[4] = (f16)b.x; p.h[5] = (f16)b.y; p.h[6] = (f16)b.z; p.h[7] = (f16)b.w;
  *(uint4*)(dst + i) = p.u;
}

// ---------------- projection GEMM (dbuf prefetch): C = epi(A @ Bw^T + bias) ----------------
template <int EPI, int MT>
__global__ __launch_bounds__(256) void gemm_proj(const float* __restrict__ A,
                                                 const f16* __restrict__ Bw,
                                                 const float* __restrict__ bias,
                                                 const int* __restrict__ mask,
                                                 f16* __restrict__ C,
                                                 f16* __restrict__ pKs,
                                                 int m_base) {
  __shared__ __attribute__((aligned(16))) f16 As[2][128][64];
  __shared__ __attribute__((aligned(16))) f16 Bs[2][128][64];
  const int tid = threadIdx.x;
  const int lane = tid & 63;
  const int l15 = lane & 15, l4 = lane >> 4;
  const int w = tid >> 6, wr = w >> 1, wc = w & 1;
  int nb, mb;
  swz<MT>(nb, mb);
  const int n0 = nb * 128;
  const int c0 = mb * 128;
  const int m0 = m_base + c0;
  const int brow = lane >> 3, bcol = (lane & 7) * 8;

  f32x4 acc[4][4];
#pragma unroll
  for (int j = 0; j < 4; j++) {
    float bv = bias[n0 + wc * 64 + j * 16 + l15];
#pragma unroll
    for (int i = 0; i < 4; i++) acc[i][j] = (f32x4){bv, bv, bv, bv};
  }

  float4 va[8];
  // prologue: stage tile 0 into buf 0
#pragma unroll
  for (int r = 0; r < 8; r++) {
    int e = r * 1024 + tid * 4;
    va[r] = *(const float4*)(A + (size_t)(m0 + (e >> 6)) * DIM + (e & 63));
  }
#pragma unroll
  for (int c = 0; c < 4; c++)
    g2l16(Bw + (size_t)(n0 + w * 32 + c * 8 + brow) * DIM + bcol,
          (char*)&Bs[0][0][0] + w * 4096 + c * 1024);
#pragma unroll
  for (int r = 0; r < 8; r++) {
    int e = r * 1024 + tid * 4;
    union { f16 hh[4]; uint2 u; } pa;
    pa.hh[0] = (f16)va[r].x; pa.hh[1] = (f16)va[r].y;
    pa.hh[2] = (f16)va[r].z; pa.hh[3] = (f16)va[r].w;
    *(uint2*)&As[0][e >> 6][e & 63] = pa.u;
  }
  __syncthreads();

  for (int t = 0; t < 16; t++) {
    const int cur = t & 1, nxt = cur ^ 1;
    const int ktn = (t + 1) * 64;
    if (t < 15) {
#pragma unroll
      for (int r = 0; r < 8; r++) {
        int e = r * 1024 + tid * 4;
        va[r] = *(const float4*)(A + (size_t)(m0 + (e >> 6)) * DIM + ktn + (e & 63));
      }
#pragma unroll
      for (int c = 0; c < 4; c++)
        g2l16(Bw + (size_t)(n0 + w * 32 + c * 8 + brow) * DIM + ktn + bcol,
              (char*)&Bs[nxt][0][0] + w * 4096 + c * 1024);
    }
#pragma unroll
    for (int ks = 0; ks < 2; ks++) {
      f16x8 af[4], bfr[4];
#pragma unroll
      for (int i = 0; i < 4; i++)
        af[i] = *(f16x8*)&As[cur][wr * 64 + i * 16 + l15][ks * 32 + l4 * 8];
#pragma unroll
      for (int j = 0; j < 4; j++)
        bfr[j] = *(f16x8*)&Bs[cur][wc * 64 + j * 16 + l15][ks * 32 + l4 * 8];
#pragma unroll
      for (int i = 0; i < 4; i++)
#pragma unroll
        for (int j = 0; j < 4; j++)
          acc[i][j] = __builtin_amdgcn_mfma_f32_16x16x32_f16(af[i], bfr[j], acc[i][j], 0, 0, 0);
    }
    if (t < 15) {
#pragma unroll
      for (int r = 0; r < 8; r++) {
        int e = r * 1024 + tid * 4;
        union { f16 hh[4]; uint2 u; } pa;
        pa.hh[0] = (f16)va[r].x; pa.hh[1] = (f16)va[r].y;
        pa.hh[2] = (f16)va[r].z; pa.hh[3] = (f16)va[r].w;
        *(uint2*)&As[nxt][e >> 6][e & 63] = pa.u;
      }
    }
    __syncthreads();
  }

  float ksm[4] = {0.f, 0.f, 0.f, 0.f};
#pragma unroll
  for (int i = 0; i < 4; i++)
#pragma unroll
    for (int j = 0; j < 4; j++) {
      const int rl = wr * 64 + i * 16 + l4 * 4;
      const int gn = n0 + wc * 64 + j * 16 + l15;
#pragma unroll
      for (int r = 0; r < 4; r++) {
        int row = rl + r;
        float x = acc[i][j][r];
        if (EPI == EPI_K) {
          x = phi_f(x);
          if (mask[m0 + row] == 0) x = 0.f;
          ksm[j] += x;
        }
        C[(size_t)(c0 + row) * DIM + gn] = (f16)x;
      }
    }
  if (EPI == EPI_K) {
#pragma unroll
    for (int j = 0; j < 4; j++) {
      float v = ksm[j];
      v += __shfl_xor(v, 16);
      v += __shfl_xor(v, 32);
      if (l4 == 0)
        pKs[(size_t)(mb * 2 + wr) * 1024 + n0 + wc * 64 + j * 16 + l15] = (f16)v;
    }
  }
}

// ---------------- KV via MFMA (unchanged) ----------------
__global__ __launch_bounds__(256) void kv_mfma(const f16* __restrict__ Kp,
                                               const f16* __restrict__ Vp,
                                               f16* __restrict__ pKV) {
  __shared__ f16 KT[64][66];
  __shared__ f16 VT[64][66];
  const int tid = threadIdx.x;
  const int lane = tid & 63;
  const int l15 = lane & 15, l4 = lane >> 4, w = tid >> 6;
  const int h = blockIdx.x;
  const int ck = blockIdx.y;
  const int bl = ck >> 3;
  const int srow0 = bl * 4096 + (ck & 7) * 512;
  const int s_loc = tid >> 2;
  const int c0 = (tid & 3) * 16;

  f32x4 acc[4];
#pragma unroll
  for (int j = 0; j < 4; j++) acc[j] = (f32x4){0.f, 0.f, 0.f, 0.f};

  for (int sub = 0; sub < 8; sub++) {
    const size_t gbase = (size_t)(srow0 + sub * 64 + s_loc) * DIM + h * 64 + c0;
    f16x8 k0 = *(const f16x8*)(Kp + gbase);
    f16x8 k1 = *(const f16x8*)(Kp + gbase + 8);
    f16x8 v0 = *(const f16x8*)(Vp + gbase);
    f16x8 v1 = *(const f16x8*)(Vp + gbase + 8);
    __syncthreads();
#pragma unroll
    for (int q = 0; q < 8; q++) {
      KT[c0 + q][s_loc] = k0[q];
      KT[c0 + 8 + q][s_loc] = k1[q];
      VT[c0 + q][s_loc] = v0[q];
      VT[c0 + 8 + q][s_loc] = v1[q];
    }
    __syncthreads();
#pragma unroll
    for (int ks = 0; ks < 2; ks++) {
      f16x8 af = *(f16x8*)&KT[w * 16 + l15][ks * 32 + l4 * 8];
#pragma unroll
      for (int j = 0; j < 4; j++) {
        f16x8 bfr = *(f16x8*)&VT[j * 16 + l15][ks * 32 + l4 * 8];
        acc[j] = __builtin_amdgcn_mfma_f32_16x16x32_f16(af, bfr, acc[j], 0, 0, 0);
      }
    }
  }
  f16* dst = pKV + (size_t)(h * 16 + ck) * 4096;
#pragma unroll
  for (int j = 0; j < 4; j++)
#pragma unroll
    for (int r = 0; r < 4; r++)
      dst[(w * 16 + l4 * 4 + r) * 64 + j * 16 + l15] = (f16)acc[j][r];
}

// ---------------- reduce (unchanged) ----------------
__global__ __launch_bounds__(256) void kv_reduce(const f16* __restrict__ pKV,
                                                 const f16* __restrict__ pKs,
                                                 f16* __restrict__ KVdh,
                                                 float* __restrict__ Ksum,
                                                 int half) {
  const int bh_l = blockIdx.x;
  const int h = bh_l & 15, bl = bh_l >> 4;
  const int bh = half * 32 + bh_l;
  const int b = half * 2 + bl;
  const int tid = threadIdx.x;
  for (int cell = tid; cell < 4096; cell += 256) {
    float s = 0.f;
#pragma unroll
    for (int c = 0; c < 8; c++) s += (float)pKV[(size_t)(h * 16 + bl * 8 + c) * 4096 + cell];
    KVdh[(size_t)bh * 4096 + cell] = (f16)s;
  }
  if (tid < 64) {
    float s = 0.f;
#pragma unroll
    for (int y = 0; y < 64; y++) s += (float)pKs[(size_t)(b * 64 + y) * 1024 + h * 64 + tid];
    Ksum[bh * 64 + tid] = s + 1e-6f;
  }
}

// ---------------- M precompute (unchanged) ----------------
__global__ __launch_bounds__(256) void m_kernel(const f16* __restrict__ Woh,
                                                const f16* __restrict__ KVdh,
                                                f16* __restrict__ Mh) {
  __shared__ __attribute__((aligned(16))) f16 As[128][64];
  __shared__ __attribute__((aligned(16))) f16 Bs[64][64];
  const int tid = threadIdx.x;
  const int lane = tid & 63;
  const int l15 = lane & 15, l4 = lane >> 4, w = tid >> 6;
  const int n0 = blockIdx.x * 128;
  const int bh = blockIdx.y;
  const int b = bh >> 4, h = bh & 15;

#pragma unroll
  for (int c = 0; c < 4; c++) {
    int row = w * 32 + c * 8 + (lane >> 3);
    int col = (lane & 7) * 8;
    g2l16(Woh + (size_t)(n0 + row) * DIM + h * 64 + col, (char*)As + w * 4096 + c * 1024);
  }
#pragma unroll
  for (int c = 0; c < 2; c++) {
    int row = w * 16 + c * 8 + (lane >> 3);
    int col = (lane & 7) * 8;
    g2l16(KVdh + (size_t)bh * 4096 + row * 64 + col, (char*)Bs + w * 2048 + c * 1024);
  }
  __syncthreads();

  f32x4 acc[2][4];
#pragma unroll
  for (int i = 0; i < 2; i++)
#pragma unroll
    for (int j = 0; j < 4; j++) acc[i][j] = (f32x4){0.f, 0.f, 0.f, 0.f};
#pragma unroll
  for (int ks = 0; ks < 2; ks++) {
    f16x8 af[2], bfr[4];
#pragma unroll
    for (int i = 0; i < 2; i++)
      af[i] = *(f16x8*)&As[w * 32 + i * 16 + l15][ks * 32 + l4 * 8];
#pragma unroll
    for (int j = 0; j < 4; j++)
      bfr[j] = *(f16x8*)&Bs[j * 16 + l15][ks * 32 + l4 * 8];
#pragma unroll
    for (int i = 0; i < 2; i++)
#pragma unroll
      for (int j = 0; j < 4; j++)
        acc[i][j] = __builtin_amdgcn_mfma_f32_16x16x32_f16(af[i], bfr[j], acc[i][j], 0, 0, 0);
  }
#pragma unroll
  for (int i = 0; i < 2; i++)
#pragma unroll
    for (int j = 0; j < 4; j++)
#pragma unroll
      for (int r = 0; r < 4; r++) {
        int nl = n0 + w * 32 + i * 16 + l4 * 4 + r;
        Mh[(size_t)b * 1048576 + (size_t)nl * DIM + h * 64 + j * 16 + l15] = (f16)acc[i][j][r];
      }
}

// ---------------- Q GEMM (dbuf prefetch) + in-register Z epilogue, FULL-M ----------------
__global__ __launch_bounds__(256) void gemm_q(const float* __restrict__ Aq,
                                              const f16* __restrict__ Wqh,
                                              const float* __restrict__ bq,
                                              const float* __restrict__ Ksum,
                                              f16* __restrict__ Ap) {
  __shared__ __attribute__((aligned(16))) f16 As[2][128][64];
  __shared__ __attribute__((aligned(16))) f16 Bs[2][128][64];
  const int tid = threadIdx.x;
  const int lane = tid & 63;
  const int l15 = lane & 15, l4 = lane >> 4;
  const int w = tid >> 6, wr = w >> 1, wc = w & 1;
  int nb, mb;
  swz<128>(nb, mb);
  const int n0 = nb * 128;
  const int c0 = mb * 128;
  const int b = c0 >> 12;
  const int bh = b * 16 + nb * 2 + wc;
  const int brow = lane >> 3, bcol = (lane & 7) * 8;

  float ks[4];
#pragma unroll
  for (int j = 0; j < 4; j++) ks[j] = Ksum[bh * 64 + j * 16 + l15];

  f32x4 acc[4][4];
#pragma unroll
  for (int j = 0; j < 4; j++) {
    float bv = bq[n0 + wc * 64 + j * 16 + l15];
#pragma unroll
    for (int i = 0; i < 4; i++) acc[i][j] = (f32x4){bv, bv, bv, bv};
  }

  float4 va[8];
#pragma unroll
  for (int r = 0; r < 8; r++) {
    int e = r * 1024 + tid * 4;
    va[r] = *(const float4*)(Aq + (size_t)(c0 + (e >> 6)) * DIM + (e & 63));
  }
#pragma unroll
  for (int c = 0; c < 4; c++)
    g2l16(Wqh + (size_t)(n0 + w * 32 + c * 8 + brow) * DIM + bcol,
          (char*)&Bs[0][0][0] + w * 4096 + c * 1024);
#pragma unroll
  for (int r = 0; r < 8; r++) {
    int e = r * 1024 + tid * 4;
    union { f16 hh[4]; uint2 u; } pa;
    pa.hh[0] = (f16)va[r].x; pa.hh[1] = (f16)va[r].y;
    pa.hh[2] = (f16)va[r].z; pa.hh[3] = (f16)va[r].w;
    *(uint2*)&As[0][e >> 6][e & 63] = pa.u;
  }
  __syncthreads();

  for (int t = 0; t < 16; t++) {
    const int cur = t & 1, nxt = cur ^ 1;
    const int ktn = (t + 1) * 64;
    if (t < 15) {
#pragma unroll
      for (int r = 0; r < 8; r++) {
        int e = r * 1024 + tid * 4;
        va[r] = *(const float4*)(Aq + (size_t)(c0 + (e >> 6)) * DIM + ktn + (e & 63));
      }
#pragma unroll
      for (int c = 0; c < 4; c++)
        g2l16(Wqh + (size_t)(n0 + w * 32 + c * 8 + brow) * DIM + ktn + bcol,
              (char*)&Bs[nxt][0][0] + w * 4096 + c * 1024);
    }
#pragma unroll
    for (int ks2 = 0; ks2 < 2; ks2++) {
      f16x8 af[4], bfr[4];
#pragma unroll
      for (int i = 0; i < 4; i++)
        af[i] = *(f16x8*)&As[cur][wr * 64 + i * 16 + l15][ks2 * 32 + l4 * 8];
#pragma unroll
      for (int j = 0; j < 4; j++)
        bfr[j] = *(f16x8*)&Bs[cur][wc * 64 + j * 16 + l15][ks2 * 32 + l4 * 8];
#pragma unroll
      for (int i = 0; i < 4; i++)
#pragma unroll
        for (int j = 0; j < 4; j++)
          acc[i][j] = __builtin_amdgcn_mfma_f32_16x16x32_f16(af[i], bfr[j], acc[i][j], 0, 0, 0);
    }
    if (t < 15) {
#pragma unroll
      for (int r = 0; r < 8; r++) {
        int e = r * 1024 + tid * 4;
        union { f16 hh[4]; uint2 u; } pa;
        pa.hh[0] = (f16)va[r].x; pa.hh[1] = (f16)va[r].y;
        pa.hh[2] = (f16)va[r].z; pa.hh[3] = (f16)va[r].w;
        *(uint2*)&As[nxt][e >> 6][e & 63] = pa.u;
      }
    }
    __syncthreads();
  }

  // in-register epilogue: phi, den via 16-lane shuffle reduce, Z-scale, write
#pragma unroll
  for (int i = 0; i < 4; i++) {
#pragma unroll
    for (int r = 0; r < 4; r++) {
      float p0 = phi_f(acc[i][0][r]);
      float p1 = phi_f(acc[i][1][r]);
      float p2 = phi_f(acc[i][2][r]);
      float p3 = phi_f(acc[i][3][r]);
      float den = p0 * ks[0] + p1 * ks[1] + p2 * ks[2] + p3 * ks[3];
      den += __shfl_xor(den, 1);
      den += __shfl_xor(den, 2);
      den += __shfl_xor(den, 4);
      den += __shfl_xor(den, 8);
      float z = 1.f / den;
      int row = wr * 64 + i * 16 + l4 * 4 + r;
      size_t base = (size_t)(c0 + row) * DIM + n0 + wc * 64 + l15;
      Ap[base] = (f16)(p0 * z);
      Ap[base + 16] = (f16)(p1 * z);
      Ap[base + 32] = (f16)(p2 * z);
      Ap[base + 48] = (f16)(p3 * z);
    }
  }
}

// ---------------- OUT GEMM (dbuf prefetch, both-DMA): out = Ap @ M_b^T + bo, FULL-M ----------------
__global__ __launch_bounds__(256) void gemm_out(const f16* __restrict__ Ap,
                                                const f16* __restrict__ Mh,
                                                const float* __restrict__ bo,
                                                float* __restrict__ Out) {
  __shared__ __attribute__((aligned(16))) f16 As[2][128][64];
  __shared__ __attribute__((aligned(16))) f16 Bs[2][128][64];
  const int tid = threadIdx.x;
  const int lane = tid & 63;
  const int l15 = lane & 15, l4 = lane >> 4;
  const int w = tid >> 6, wr = w >> 1, wc = w & 1;
  int nb, mb;
  swz<128>(nb, mb);
  const int n0 = nb * 128;
  const int c0 = mb * 128;
  const int b = c0 >> 12;
  const f16* B = Mh + (size_t)b * 1048576;
  const int brow = lane >> 3, bcol = (lane & 7) * 8;

  f32x4 acc[4][4];
#pragma unroll
  for (int j = 0; j < 4; j++) {
    float bv = bo[n0 + wc * 64 + j * 16 + l15];
#pragma unroll
    for (int i = 0; i < 4; i++) acc[i][j] = (f32x4){bv, bv, bv, bv};
  }

#pragma unroll
  for (int c = 0; c < 4; c++) {
    g2l16(Ap + (size_t)(c0 + w * 32 + c * 8 + brow) * DIM + bcol,
          (char*)&As[0][0][0] + w * 4096 + c * 1024);
    g2l16(B + (size_t)(n0 + w * 32 + c * 8 + brow) * DIM + bcol,
          (char*)&Bs[0][0][0] + w * 4096 + c * 1024);
  }
  __syncthreads();

  for (int t = 0; t < 16; t++) {
    const int cur = t & 1, nxt = cur ^ 1;
    const int ktn = (t + 1) * 64;
    if (t < 15) {
#pragma unroll
      for (int c = 0; c < 4; c++) {
        g2l16(Ap + (size_t)(c0 + w * 32 + c * 8 + brow) * DIM + ktn + bcol,
              (char*)&As[nxt][0][0] + w * 4096 + c * 1024);
        g2l16(B + (size_t)(n0 + w * 32 + c * 8 + brow) * DIM + ktn + bcol,
              (char*)&Bs[nxt][0][0] + w * 4096 + c * 1024);
      }
    }
#pragma unroll
    for (int ks = 0; ks < 2; ks++) {
      f16x8 af[4], bfr[4];
#pragma unroll
      for (int i = 0; i < 4; i++)
        af[i] = *(f16x8*)&As[cur][wr * 64 + i * 16 + l15][ks * 32 + l4 * 8];
#pragma unroll
      for (int j = 0; j < 4; j++)
        bfr[j] = *(f16x8*)&Bs[cur][wc * 64 + j * 16 + l15][ks * 32 + l4 * 8];
#pragma unroll
      for (int i = 0; i < 4; i++)
#pragma unroll
        for (int j = 0; j < 4; j++)
          acc[i][j] = __builtin_amdgcn_mfma_f32_16x16x32_f16(af[i], bfr[j], acc[i][j], 0, 0, 0);
    }
    __syncthreads();
  }

#pragma unroll
  for (int i = 0; i < 4; i++)
#pragma unroll
    for (int j = 0; j < 4; j++) {
      const int rl = wr * 64 + i * 16 + l4 * 4;
      const int gn = n0 + wc * 64 + j * 16 + l15;
#pragma unroll
      for (int r = 0; r < 4; r++)
        Out[(size_t)(c0 + rl + r) * DIM + gn] = acc[i][j][r];
    }
}

extern "C" void kernel_launch(void* const* d_in, const int* in_sizes, int n_in,
                              void* d_out, int out_size, void* d_ws, size_t ws_size,
                              hipStream_t stream) {
  (void)in_sizes; (void)n_in; (void)out_size; (void)ws_size;
  const float* query = (const float*)d_in[0];
  const float* key = (const float*)d_in[1];
  const float* value = (const float*)d_in[2];
  const int* kmask = (const int*)d_in[3];
  const float* Wq = (const float*)d_in[4];
  const float* bq = (const float*)d_in[5];
  const float* Wk = (const float*)d_in[6];
  const float* bk = (const float*)d_in[7];
  const float* Wv = (const float*)d_in[8];
  const float* bv = (const float*)d_in[9];
  const float* Wo = (const float*)d_in[10];
  const float* bo = (const float*)d_in[11];

  // workspace (peak ~55.1 MiB; exact R9 layout, proven safe)
  char* ws = (char*)d_ws;
  const size_t MB = 1 << 20;
  f16* W0 = (f16*)(ws);                // 2 MiB: Wkh -> Wqh
  f16* W1 = (f16*)(ws + 2 * MB);       // 2 MiB: Wvh -> Woh
  f16* Kp = (f16*)(ws + 4 * MB);       // 32 MiB FULL ; stage2: Ap
  f16* Vp = (f16*)(ws + 36 * MB);      // 16 MiB (half) ; stage2: Mh (8 MiB)
  f16* pKV = (f16*)(ws + 52 * MB);     // 2 MiB (per-half scratch)
  f16* pKs = (f16*)(ws + 54 * MB);     // [256][1024] f16 = 512 KiB (FULL)
  f16* KVdh = (f16*)(ws + 54 * MB + 512 * 1024);      // 512 KiB
  float* Ksum = (float*)(ws + 55 * MB);               // 16 KiB
  f16* Ap = Kp;
  f16* Mh = Vp;

  dim3 blk(256);
  cvt8<<<512, blk, 0, stream>>>(Wk, W0);
  cvt8<<<512, blk, 0, stream>>>(Wv, W1);

  // stage 1: full-M K projection, per-half V projection + KV
  gemm_proj<EPI_K, 128><<<dim3(8, 128), blk, 0, stream>>>(key, W0, bk, kmask, Kp, pKs, 0);
  for (int half = 0; half < 2; half++) {
    int mb = half * 8192;
    gemm_proj<EPI_V, 64><<<dim3(8, 64), blk, 0, stream>>>(value, W1, bv, nullptr, Vp, nullptr, mb);
    kv_mfma<<<dim3(16, 16), blk, 0, stream>>>(Kp + (size_t)mb * DIM, Vp, pKV);
    kv_reduce<<<32, blk, 0, stream>>>(pKV, pKs, KVdh, Ksum, half);
  }

  // stage 2: full-M Q -> A', M precompute, full-M OUT
  cvt8<<<512, blk, 0, stream>>>(Wq, W0);
  cvt8<<<512, blk, 0, stream>>>(Wo, W1);
  m_kernel<<<dim3(8, 64), blk, 0, stream>>>(W1, KVdh, Mh);
  gemm_q<<<dim3(8, 128), blk, 0, stream>>>(query, W0, bq, Ksum, Ap);
  gemm_out<<<dim3(8, 128), blk, 0, stream>>>(Ap, Mh, bo, (float*)d_out);
}